// Round 1
// baseline (208.119 us; speedup 1.0000x reference)
//
#include <hip/hip_runtime.h>
#include <math.h>

#define B_  8
#define N_  128
#define T_  256
#define L_  32
#define H_  128
#define TT_ 224   // T - L

__device__ __forceinline__ float fsig(float x) {
    return __builtin_amdgcn_rcpf(1.0f + __expf(-x));
}
__device__ __forceinline__ float ftanh_(float x) {
    return 1.0f - 2.0f * __builtin_amdgcn_rcpf(1.0f + __expf(2.0f * x));
}

// ---------------------------------------------------------------------------
// Kernel 0: Wsum[n,h] = sum_j W_fc[n,j,h]; bsum[n] = sum_j b_fc[n,j]
// ---------------------------------------------------------------------------
__global__ __launch_bounds__(128)
void k_pre(const float* __restrict__ W_fc, const float* __restrict__ b_fc,
           float* __restrict__ wsum, float* __restrict__ bsum) {
    int n = blockIdx.x;
    int h = threadIdx.x;                      // 128 threads
    const float* W = W_fc + (size_t)n * N_ * H_;
    float s = 0.f;
    #pragma unroll 8
    for (int j = 0; j < N_; ++j) s += W[j * H_ + h];
    wsum[n * H_ + h] = s;

    float bv = b_fc[n * N_ + h];
    #pragma unroll
    for (int off = 32; off > 0; off >>= 1) bv += __shfl_down(bv, off, 64);
    __shared__ float bp[2];
    if ((h & 63) == 0) bp[h >> 6] = bv;
    __syncthreads();
    if (h == 0) bsum[n] = bp[0] + bp[1];
}

// ---------------------------------------------------------------------------
// Kernel 1: per (b,n) block. Computes gates (gi,gg,go only — gf is dead),
// h = sig(go)*tanh(sig(gi)*tanh(gg)), and reduces online into:
//   Hd[b,n,h]   = sum_t h/x[b,n,L+t]
//   Dinv[b,n]   = sum_t 1/x[b,n,L+t]
//   X_hat[b,t,n]= sum_h h*Wsum[n,h] + bsum[n] + 1e-6
// Thread map: h = tid&127, tg = tid>>7 (two halves of t-range, 112 each).
// ---------------------------------------------------------------------------
__global__ __launch_bounds__(256, 2)
void k_main(const float* __restrict__ x, const float* __restrict__ W_ih,
            const float* __restrict__ b_ih, const float* __restrict__ b_hh,
            const float* __restrict__ wsum, const float* __restrict__ bsum,
            float* __restrict__ Hd, float* __restrict__ Dinv,
            float* __restrict__ xhat) {
    const int n   = blockIdx.x;
    const int b   = blockIdx.y;
    const int tid = threadIdx.x;
    const int h    = tid & 127;
    const int tg   = tid >> 7;   // 0 or 1
    const int wid  = tid >> 6;   // 0..3
    const int lane = tid & 63;

    __shared__ float xs[T_];
    __shared__ float xr[TT_];
    __shared__ float bia[3 * H_];   // [0:128)=gi bias, [128:256)=gg, [256:384)=go
    __shared__ float ws_s[H_];
    __shared__ float xh_w[4][112];
    __shared__ float hd_s[H_];
    __shared__ float red[4];

    // ---- stage x, biases, wsum ----
    xs[tid] = x[((size_t)b * N_ + n) * T_ + tid];
    {
        const float* bi = b_ih + (size_t)n * 4 * H_;
        const float* bh = b_hh + (size_t)n * 4 * H_;
        if (tid < 128) {
            bia[tid]       = bi[tid]       + bh[tid];        // gi: ch h
            bia[256 + tid] = bi[384 + tid] + bh[384 + tid];  // go: ch 384+h
        } else {
            bia[tid] = bi[128 + tid] + bh[128 + tid];        // gg: ch 256+(tid-128)
            ws_s[tid - 128] = wsum[n * H_ + (tid - 128)];
        }
    }
    __syncthreads();
    if (tid < TT_) xr[tid] = 1.0f / xs[L_ + tid];
    __syncthreads();

    // ---- W rows into registers (3 gates x 32 floats) ----
    const float4* Wi4 = (const float4*)(W_ih + ((size_t)n * 4 * H_ + h)          * L_);
    const float4* Wg4 = (const float4*)(W_ih + ((size_t)n * 4 * H_ + 2 * H_ + h) * L_);
    const float4* Wo4 = (const float4*)(W_ih + ((size_t)n * 4 * H_ + 3 * H_ + h) * L_);
    float wiF[32], wgF[32], woF[32];
    #pragma unroll
    for (int i = 0; i < 8; ++i) {
        float4 a = Wi4[i], g = Wg4[i], o = Wo4[i];
        wiF[4*i+0]=a.x; wiF[4*i+1]=a.y; wiF[4*i+2]=a.z; wiF[4*i+3]=a.w;
        wgF[4*i+0]=g.x; wgF[4*i+1]=g.y; wgF[4*i+2]=g.z; wgF[4*i+3]=g.w;
        woF[4*i+0]=o.x; woF[4*i+1]=o.y; woF[4*i+2]=o.z; woF[4*i+3]=o.w;
    }
    const float bii = bia[h], bgg = bia[128 + h], boo = bia[256 + h];
    const float wsh = ws_s[h];
    float hd_acc = 0.f;
    const int t0 = tg * 112;

    // ---- main loop: 28 groups of 4 t each ----
    for (int grp = 0; grp < 28; ++grp) {
        const int tb = t0 + grp * 4;           // multiple of 4 -> 16B-aligned LDS reads
        float xv[36];
        #pragma unroll
        for (int i = 0; i < 9; ++i) {
            float4 v = *(const float4*)&xs[tb + 4 * i];   // broadcast ds_read_b128
            xv[4*i+0]=v.x; xv[4*i+1]=v.y; xv[4*i+2]=v.z; xv[4*i+3]=v.w;
        }
        #pragma unroll
        for (int dt = 0; dt < 4; ++dt) {
            float gi_ = bii, gg_ = bgg, go_ = boo;
            #pragma unroll
            for (int l = 0; l < L_; ++l) {
                const float xl = xv[dt + l];
                gi_ = fmaf(xl, wiF[l], gi_);
                gg_ = fmaf(xl, wgF[l], gg_);
                go_ = fmaf(xl, woF[l], go_);
            }
            const float c  = fsig(gi_) * ftanh_(gg_);
            const float hh = fsig(go_) * ftanh_(c);
            hd_acc = fmaf(hh, xr[tb + dt], hd_acc);
            float p = hh * wsh;
            #pragma unroll
            for (int off = 32; off > 0; off >>= 1) p += __shfl_down(p, off, 64);
            if (lane == 0) xh_w[wid][tb + dt - t0] = p;
        }
    }

    // ---- Hd combine (tg0 + tg1) ----
    if (tg == 0) hd_s[h] = hd_acc;
    __syncthreads();   // hd_s ready; all xh_w writes visible
    if (tg == 1) Hd[((size_t)b * N_ + n) * H_ + h] = hd_s[h] + hd_acc;

    // ---- X_hat writeout ----
    if (tid < TT_) {
        const int t = tid;
        const float v = (t < 112) ? (xh_w[0][t] + xh_w[1][t])
                                  : (xh_w[2][t - 112] + xh_w[3][t - 112]);
        xhat[((size_t)b * TT_ + t) * N_ + n] = v + bsum[n] + 1e-6f;
    }

    // ---- Dinv ----
    float dv = (tid < TT_) ? xr[tid] : 0.f;
    #pragma unroll
    for (int off = 32; off > 0; off >>= 1) dv += __shfl_down(dv, off, 64);
    if (lane == 0) red[wid] = dv;
    __syncthreads();
    if (tid == 0) Dinv[b * N_ + n] = red[0] + red[1] + red[2] + red[3];
}

// ---------------------------------------------------------------------------
// Kernel 2: G[b,j,n] = (1/224)*(sum_h W_fc[n,j,h]*Hd[b,n,h] + b_fc[n,j]*Dinv[b,n])
// ---------------------------------------------------------------------------
__global__ __launch_bounds__(128)
void k_g(const float* __restrict__ W_fc, const float* __restrict__ b_fc,
         const float* __restrict__ Hd, const float* __restrict__ Dinv,
         float* __restrict__ G) {
    const int n = blockIdx.x;
    const int j = threadIdx.x;   // 128 threads
    __shared__ float hd_s[B_][H_];
    __shared__ float dinv_s[B_];
    for (int i = threadIdx.x; i < B_ * H_; i += 128) {
        const int bb = i >> 7, hh = i & 127;
        hd_s[bb][hh] = Hd[((size_t)bb * N_ + n) * H_ + hh];
    }
    if (threadIdx.x < B_) dinv_s[threadIdx.x] = Dinv[threadIdx.x * N_ + n];
    __syncthreads();

    const float* W = W_fc + ((size_t)n * N_ + j) * H_;
    float acc[B_];
    #pragma unroll
    for (int bb = 0; bb < B_; ++bb) acc[bb] = 0.f;
    #pragma unroll 4
    for (int hh = 0; hh < H_; ++hh) {
        const float w = W[hh];
        #pragma unroll
        for (int bb = 0; bb < B_; ++bb) acc[bb] = fmaf(w, hd_s[bb][hh], acc[bb]);
    }
    const float bj = b_fc[n * N_ + j];
    const float inv = 1.0f / 224.0f;
    #pragma unroll
    for (int bb = 0; bb < B_; ++bb)
        G[(size_t)bb * N_ * N_ + (size_t)j * N_ + n] = (acc[bb] + bj * dinv_s[bb]) * inv;
}

// ---------------------------------------------------------------------------
extern "C" void kernel_launch(void* const* d_in, const int* in_sizes, int n_in,
                              void* d_out, int out_size, void* d_ws, size_t ws_size,
                              hipStream_t stream) {
    const float* x    = (const float*)d_in[0];
    const float* W_ih = (const float*)d_in[1];
    const float* b_ih = (const float*)d_in[2];
    const float* b_hh = (const float*)d_in[3];
    const float* W_fc = (const float*)d_in[4];
    const float* b_fc = (const float*)d_in[5];

    float* G    = (float*)d_out;                       // B*N*N = 131072
    float* xhat = (float*)d_out + (size_t)B_ * N_ * N_; // B*TT*N = 229376

    float* wsum = (float*)d_ws;          // 16384
    float* bsum = wsum + N_ * H_;        // 128
    float* Hd   = bsum + N_;             // 131072
    float* Dinv = Hd + (size_t)B_ * N_ * H_; // 1024

    k_pre<<<dim3(N_), dim3(128), 0, stream>>>(W_fc, b_fc, wsum, bsum);
    k_main<<<dim3(N_, B_), dim3(256), 0, stream>>>(x, W_ih, b_ih, b_hh,
                                                   wsum, bsum, Hd, Dinv, xhat);
    k_g<<<dim3(N_), dim3(128), 0, stream>>>(W_fc, b_fc, Hd, Dinv, G);
}

// Round 2
// 201.165 us; speedup vs baseline: 1.0346x; 1.0346x over previous
//
#include <hip/hip_runtime.h>
#include <math.h>

#define B_  8
#define N_  128
#define T_  256
#define L_  32
#define H_  128
#define TT_ 224   // T - L

__device__ __forceinline__ float fsig(float x) {
    return __builtin_amdgcn_rcpf(1.0f + __expf(-x));
}
__device__ __forceinline__ float ftanh_(float x) {
    return 1.0f - 2.0f * __builtin_amdgcn_rcpf(1.0f + __expf(2.0f * x));
}

// ---------------------------------------------------------------------------
// Kernel 0: Wsum[n,h] = sum_j W_fc[n,j,h]; bsum[n] = sum_j b_fc[n,j]
// 512 threads: 4-way j-split for memory-latency parallelism.
// ---------------------------------------------------------------------------
__global__ __launch_bounds__(512)
void k_pre(const float* __restrict__ W_fc, const float* __restrict__ b_fc,
           float* __restrict__ wsum, float* __restrict__ bsum) {
    const int n  = blockIdx.x;
    const int h  = threadIdx.x & 127;
    const int jq = threadIdx.x >> 7;          // 0..3
    const float* W = W_fc + (size_t)n * N_ * H_ + (size_t)jq * 32 * H_;
    float s = 0.f;
    #pragma unroll 8
    for (int j = 0; j < 32; ++j) s += W[j * H_ + h];
    __shared__ float part[4][128];
    __shared__ float bp[2];
    part[jq][h] = s;

    if (threadIdx.x < 128) {
        float bv = b_fc[n * N_ + threadIdx.x];
        #pragma unroll
        for (int off = 32; off > 0; off >>= 1) bv += __shfl_down(bv, off, 64);
        if ((threadIdx.x & 63) == 0) bp[threadIdx.x >> 6] = bv;
    }
    __syncthreads();
    if (threadIdx.x < 128)
        wsum[n * H_ + h] = part[0][h] + part[1][h] + part[2][h] + part[3][h];
    if (threadIdx.x == 0) bsum[n] = bp[0] + bp[1];
}

// ---------------------------------------------------------------------------
// Kernel 1: per (b,n) block. Gates gi,gg,go (gf is dead), activations,
// online reductions into Hd, Dinv, X_hat.
// __launch_bounds__(256,1): allocator may use up to 512 VGPRs so the
// 96 weight floats + 36 x-window floats stay register-resident (at (256,2)
// the compiler allocated only 80 VGPRs and streamed weights in-loop).
// ---------------------------------------------------------------------------
__global__ __launch_bounds__(256, 1)
void k_main(const float* __restrict__ x, const float* __restrict__ W_ih,
            const float* __restrict__ b_ih, const float* __restrict__ b_hh,
            const float* __restrict__ wsum, const float* __restrict__ bsum,
            float* __restrict__ Hd, float* __restrict__ Dinv,
            float* __restrict__ xhat) {
    const int n   = blockIdx.x;
    const int b   = blockIdx.y;
    const int tid = threadIdx.x;
    const int h    = tid & 127;
    const int tg   = tid >> 7;   // 0 or 1
    const int wid  = tid >> 6;   // 0..3
    const int lane = tid & 63;

    __shared__ float xs[T_];
    __shared__ float xr[TT_];
    __shared__ float bia[3 * H_];
    __shared__ float ws_s[H_];
    __shared__ float xh_w[4][112];
    __shared__ float hd_s[H_];
    __shared__ float red[4];

    // ---- issue W row loads early (independent of LDS) ----
    const float4* Wi4 = (const float4*)(W_ih + ((size_t)n * 4 * H_ + h)          * L_);
    const float4* Wg4 = (const float4*)(W_ih + ((size_t)n * 4 * H_ + 2 * H_ + h) * L_);
    const float4* Wo4 = (const float4*)(W_ih + ((size_t)n * 4 * H_ + 3 * H_ + h) * L_);
    float wiF[32], wgF[32], woF[32];
    #pragma unroll
    for (int i = 0; i < 8; ++i) {
        float4 a = Wi4[i], g = Wg4[i], o = Wo4[i];
        wiF[4*i+0]=a.x; wiF[4*i+1]=a.y; wiF[4*i+2]=a.z; wiF[4*i+3]=a.w;
        wgF[4*i+0]=g.x; wgF[4*i+1]=g.y; wgF[4*i+2]=g.z; wgF[4*i+3]=g.w;
        woF[4*i+0]=o.x; woF[4*i+1]=o.y; woF[4*i+2]=o.z; woF[4*i+3]=o.w;
    }

    // ---- stage x, biases, wsum ----
    xs[tid] = x[((size_t)b * N_ + n) * T_ + tid];
    {
        const float* bi = b_ih + (size_t)n * 4 * H_;
        const float* bh = b_hh + (size_t)n * 4 * H_;
        if (tid < 128) {
            bia[tid]       = bi[tid]       + bh[tid];        // gi
            bia[256 + tid] = bi[384 + tid] + bh[384 + tid];  // go
        } else {
            bia[tid] = bi[128 + tid] + bh[128 + tid];        // gg
            ws_s[tid - 128] = wsum[n * H_ + (tid - 128)];
        }
    }
    __syncthreads();
    if (tid < TT_) xr[tid] = 1.0f / xs[L_ + tid];
    __syncthreads();

    const float bii = bia[h], bgg = bia[128 + h], boo = bia[256 + h];
    const float wsh = ws_s[h];
    float hd_acc = 0.f;
    const int t0 = tg * 112;

    // ---- main loop: 28 groups of 4 t each ----
    for (int grp = 0; grp < 28; ++grp) {
        const int tb = t0 + grp * 4;
        float xv[36];
        #pragma unroll
        for (int i = 0; i < 9; ++i) {
            float4 v = *(const float4*)&xs[tb + 4 * i];   // broadcast ds_read_b128
            xv[4*i+0]=v.x; xv[4*i+1]=v.y; xv[4*i+2]=v.z; xv[4*i+3]=v.w;
        }
        #pragma unroll
        for (int dt = 0; dt < 4; ++dt) {
            float gi_ = bii, gg_ = bgg, go_ = boo;
            #pragma unroll
            for (int l = 0; l < L_; ++l) {
                const float xl = xv[dt + l];
                gi_ = fmaf(xl, wiF[l], gi_);
                gg_ = fmaf(xl, wgF[l], gg_);
                go_ = fmaf(xl, woF[l], go_);
            }
            const float c  = fsig(gi_) * ftanh_(gg_);
            const float hh = fsig(go_) * ftanh_(c);
            hd_acc = fmaf(hh, xr[tb + dt], hd_acc);
            float p = hh * wsh;
            #pragma unroll
            for (int off = 32; off > 0; off >>= 1) p += __shfl_down(p, off, 64);
            if (lane == 0) xh_w[wid][tb + dt - t0] = p;
        }
    }

    // ---- Hd combine ----
    if (tg == 0) hd_s[h] = hd_acc;
    __syncthreads();
    if (tg == 1) Hd[((size_t)b * N_ + n) * H_ + h] = hd_s[h] + hd_acc;

    // ---- X_hat writeout ----
    if (tid < TT_) {
        const int t = tid;
        const float v = (t < 112) ? (xh_w[0][t] + xh_w[1][t])
                                  : (xh_w[2][t - 112] + xh_w[3][t - 112]);
        xhat[((size_t)b * TT_ + t) * N_ + n] = v + bsum[n] + 1e-6f;
    }

    // ---- Dinv ----
    float dv = (tid < TT_) ? xr[tid] : 0.f;
    #pragma unroll
    for (int off = 32; off > 0; off >>= 1) dv += __shfl_down(dv, off, 64);
    if (lane == 0) red[wid] = dv;
    __syncthreads();
    if (tid == 0) Dinv[b * N_ + n] = red[0] + red[1] + red[2] + red[3];
}

// ---------------------------------------------------------------------------
// Kernel 2: G[b,j,n] = (1/224)*(sum_h W_fc[n,j,h]*Hd[b,n,h] + b_fc[n,j]*Dinv[b,n])
// 256 threads: 2-way h-split, float4 W reads.
// ---------------------------------------------------------------------------
__global__ __launch_bounds__(256)
void k_g(const float* __restrict__ W_fc, const float* __restrict__ b_fc,
         const float* __restrict__ Hd, const float* __restrict__ Dinv,
         float* __restrict__ G) {
    const int n   = blockIdx.x;
    const int j   = threadIdx.x & 127;
    const int hh2 = threadIdx.x >> 7;   // 0 or 1
    __shared__ float hd_s[B_][H_];
    __shared__ float dinv_s[B_];
    __shared__ float pacc[128][B_];
    for (int i = threadIdx.x; i < B_ * H_; i += 256) {
        hd_s[i >> 7][i & 127] = Hd[((size_t)(i >> 7) * N_ + n) * H_ + (i & 127)];
    }
    if (threadIdx.x < B_) dinv_s[threadIdx.x] = Dinv[threadIdx.x * N_ + n];
    __syncthreads();

    const float4* W4 = (const float4*)(W_fc + ((size_t)n * N_ + j) * H_ + hh2 * 64);
    float acc[B_];
    #pragma unroll
    for (int bb = 0; bb < B_; ++bb) acc[bb] = 0.f;
    #pragma unroll
    for (int q = 0; q < 16; ++q) {
        const float4 w = W4[q];
        const int hb = hh2 * 64 + q * 4;
        #pragma unroll
        for (int bb = 0; bb < B_; ++bb) {
            acc[bb] = fmaf(w.x, hd_s[bb][hb + 0],
                      fmaf(w.y, hd_s[bb][hb + 1],
                      fmaf(w.z, hd_s[bb][hb + 2],
                      fmaf(w.w, hd_s[bb][hb + 3], acc[bb]))));
        }
    }
    if (hh2 == 1) {
        #pragma unroll
        for (int bb = 0; bb < B_; ++bb) pacc[j][bb] = acc[bb];
    }
    __syncthreads();
    if (hh2 == 0) {
        const float bj  = b_fc[n * N_ + j];
        const float inv = 1.0f / 224.0f;
        #pragma unroll
        for (int bb = 0; bb < B_; ++bb)
            G[(size_t)bb * N_ * N_ + (size_t)j * N_ + n] =
                (acc[bb] + pacc[j][bb] + bj * dinv_s[bb]) * inv;
    }
}

// ---------------------------------------------------------------------------
extern "C" void kernel_launch(void* const* d_in, const int* in_sizes, int n_in,
                              void* d_out, int out_size, void* d_ws, size_t ws_size,
                              hipStream_t stream) {
    const float* x    = (const float*)d_in[0];
    const float* W_ih = (const float*)d_in[1];
    const float* b_ih = (const float*)d_in[2];
    const float* b_hh = (const float*)d_in[3];
    const float* W_fc = (const float*)d_in[4];
    const float* b_fc = (const float*)d_in[5];

    float* G    = (float*)d_out;                        // B*N*N = 131072
    float* xhat = (float*)d_out + (size_t)B_ * N_ * N_; // B*TT*N = 229376

    float* wsum = (float*)d_ws;              // 16384
    float* bsum = wsum + N_ * H_;            // 128
    float* Hd   = bsum + N_;                 // 131072
    float* Dinv = Hd + (size_t)B_ * N_ * H_; // 1024

    k_pre<<<dim3(N_), dim3(512), 0, stream>>>(W_fc, b_fc, wsum, bsum);
    k_main<<<dim3(N_, B_), dim3(256), 0, stream>>>(x, W_ih, b_ih, b_hh,
                                                   wsum, bsum, Hd, Dinv, xhat);
    k_g<<<dim3(N_), dim3(256), 0, stream>>>(W_fc, b_fc, Hd, Dinv, G);
}